// Round 3
// baseline (92.340 us; speedup 1.0000x reference)
//
#include <hip/hip_runtime.h>
#include <stdint.h>

#define NSEG 4096

// Accumulator: acc[4*seg + {0,1,2}] = {sum x0, sum x1, count}.

// Each lane owns 16 consecutive points (256 B): 4x int4 ids + 8x float4 x.
// Fast path (~98.4% of chunks): first id == last id (sorted => uniform chunk),
// pure tree sum. Slow path: serial run accumulation with direct atomic flush
// of completed intra-lane runs. Then one segmented Kogge-Stone scan over the
// 64 lane aggregates; run-tail lanes flush with 3 atomics.
__global__ __launch_bounds__(256) void seg_reduce(
    const float4* __restrict__ x4,   // x as float4 (2 points each)
    const int4*   __restrict__ ids4, // ids as int4
    float* __restrict__ acc,         // [4*NSEG]
    int nchunk)                      // chunks of 16 points
{
    const int lane = threadIdx.x & 63;
    const int idx = blockIdx.x * blockDim.x + threadIdx.x;
    const bool valid = idx < nchunk;

    int4 id0, id1, id2, id3;
    float4 xv[8];
    if (valid) {
        id0 = ids4[4 * idx + 0];
        id1 = ids4[4 * idx + 1];
        id2 = ids4[4 * idx + 2];
        id3 = ids4[4 * idx + 3];
        #pragma unroll
        for (int i = 0; i < 8; ++i) xv[i] = x4[8 * idx + i];
    } else {
        id0 = make_int4(-1, -1, -1, -1);
        id1 = id0; id2 = id0; id3 = id0;
        #pragma unroll
        for (int i = 0; i < 8; ++i) xv[i] = make_float4(0.f, 0.f, 0.f, 0.f);
    }

    int cur;
    float s0, s1, cnt;

    if (id0.x == id3.w) {
        // Uniform chunk (ids sorted => all 16 equal). Invalid lanes land here too.
        cur = id0.x;
        float a0 = 0.f, a1 = 0.f;
        #pragma unroll
        for (int i = 0; i < 8; ++i) {
            a0 += xv[i].x + xv[i].z;
            a1 += xv[i].y + xv[i].w;
        }
        s0 = a0; s1 = a1;
        cnt = valid ? 16.f : 0.f;
    } else {
        // Boundary chunk (rare): serial run accumulation.
        int segs[16];
        segs[0] = id0.x;  segs[1] = id0.y;  segs[2] = id0.z;  segs[3] = id0.w;
        segs[4] = id1.x;  segs[5] = id1.y;  segs[6] = id1.z;  segs[7] = id1.w;
        segs[8] = id2.x;  segs[9] = id2.y;  segs[10] = id2.z; segs[11] = id2.w;
        segs[12] = id3.x; segs[13] = id3.y; segs[14] = id3.z; segs[15] = id3.w;
        float p0[16], p1[16];
        #pragma unroll
        for (int i = 0; i < 8; ++i) {
            p0[2 * i]     = xv[i].x;  p1[2 * i]     = xv[i].y;
            p0[2 * i + 1] = xv[i].z;  p1[2 * i + 1] = xv[i].w;
        }
        cur = segs[0]; s0 = p0[0]; s1 = p1[0]; cnt = 1.f;
        #pragma unroll
        for (int i = 1; i < 16; ++i) {
            if (segs[i] != cur) {
                atomicAdd(&acc[4 * cur + 0], s0);
                atomicAdd(&acc[4 * cur + 1], s1);
                atomicAdd(&acc[4 * cur + 2], cnt);
                cur = segs[i]; s0 = p0[i]; s1 = p1[i]; cnt = 1.f;
            } else {
                s0 += p0[i]; s1 += p1[i]; cnt += 1.f;
            }
        }
    }

    // Segmented scan over lane aggregates keyed by cur.
    int prev = __shfl_up(cur, 1);
    bool head = (lane == 0) || (prev != cur);
    uint64_t heads = __ballot(head);
    uint64_t below = heads & (~0ull >> (63 - lane));
    int run_start = 63 - __builtin_clzll(below);

    #pragma unroll
    for (int d = 1; d < 64; d <<= 1) {
        float t0 = __shfl_up(s0, d);
        float t1 = __shfl_up(s1, d);
        float tc = __shfl_up(cnt, d);
        if (lane - d >= run_start) { s0 += t0; s1 += t1; cnt += tc; }
    }

    bool tail = (lane == 63) || ((heads >> (lane + 1)) & 1ull);
    if (tail && cur >= 0) {
        atomicAdd(&acc[4 * cur + 0], s0);
        atomicAdd(&acc[4 * cur + 1], s1);
        atomicAdd(&acc[4 * cur + 2], cnt);
    }
}

// out[s, f] = a0[s]*W[0][f] + a1[s]*W[1][f] + cnt[s]*b[f], float4-vectorized.
__global__ __launch_bounds__(256) void epilogue(
    const float*  __restrict__ acc,  // [4*NSEG]
    const float4* __restrict__ W4,   // [2][64] -> [2][16] float4
    const float4* __restrict__ b4,   // [64] -> [16] float4
    float4* __restrict__ out4)       // [NSEG][16] float4
{
    int idx = blockIdx.x * blockDim.x + threadIdx.x;  // 65536 threads
    int s = idx >> 4;
    int f = idx & 15;
    float a0 = acc[4 * s], a1 = acc[4 * s + 1], c = acc[4 * s + 2];
    float4 w0 = W4[f], w1 = W4[16 + f], bb = b4[f];
    float4 o;
    o.x = a0 * w0.x + a1 * w1.x + c * bb.x;
    o.y = a0 * w0.y + a1 * w1.y + c * bb.y;
    o.z = a0 * w0.z + a1 * w1.z + c * bb.z;
    o.w = a0 * w0.w + a1 * w1.w + c * bb.w;
    out4[idx] = o;
}

extern "C" void kernel_launch(void* const* d_in, const int* in_sizes, int n_in,
                              void* d_out, int out_size, void* d_ws, size_t ws_size,
                              hipStream_t stream) {
    const float4* x4   = (const float4*)d_in[0];  // [N,2] fp32
    const int4*   ids4 = (const int4*)d_in[1];    // [N] int32, sorted
    const float4* W4   = (const float4*)d_in[2];  // [2,64] fp32
    const float4* b4   = (const float4*)d_in[3];  // [64] fp32
    float4* out4 = (float4*)d_out;                // [4096,64] fp32

    const int n = in_sizes[1];                    // 4,000,000
    const int nchunk = n / 16;                    // 250,000 chunks of 16 points
    const int nblocks = (nchunk + 255) / 256;     // 977

    float* acc = (float*)d_ws;                    // [4*NSEG]

    hipMemsetAsync(d_ws, 0, 4 * NSEG * sizeof(float), stream);
    seg_reduce<<<nblocks, 256, 0, stream>>>(x4, ids4, acc, nchunk);
    epilogue<<<(NSEG * 64 / 4) / 256, 256, 0, stream>>>(acc, W4, b4, out4);
}

// Round 5
// 92.283 us; speedup vs baseline: 1.0006x; 1.0006x over previous
//
#include <hip/hip_runtime.h>
#include <stdint.h>

#define NSEG 4096

// Accumulator: acc[4*seg + {0,1,2}] = {sum x0, sum x1, count}.
//
// Wave-coalesced layout, id<->x correspondence FIXED (r4 bug):
// Each wave owns 4 rounds of 256 consecutive points. In round j:
//   lane i handles the 4 consecutive points  base + 256j + 4i .. +3
//   ids: ids4[m_base + 64j + i]          (16 B lane-stride, perfectly coalesced)
//   x:   x4[k_base + 128j + 2i], [ +1 ]  (two loads over one contiguous 2 KiB span)
// Uniform-group fast path (~99.6%), per-round segmented Kogge-Stone scan over
// lane aggregates, run-tail lanes flush {s0,s1,cnt} with 3 atomics to one line.
__global__ __launch_bounds__(256) void seg_reduce(
    const float4* __restrict__ x4,   // x as float4 (2 points each)
    const int4*   __restrict__ ids4, // ids as int4 (4 points each)
    float* __restrict__ acc,         // [4*NSEG]
    int n)                           // total points
{
    const int lane = threadIdx.x & 63;
    const int wave = threadIdx.x >> 6;
    const int wc   = blockIdx.x * 4 + wave;   // wave-chunk (1024 points)
    const int base_pt = wc * 1024;
    if (base_pt >= n) return;

    const int m_base = base_pt >> 2;          // ids4 base
    const int k_base = base_pt >> 1;          // x4 base

    #pragma unroll
    for (int j = 0; j < 4; ++j) {
        const int pt0 = base_pt + 256 * j + 4 * lane;   // first point of my group
        const bool v = pt0 < n;                         // n%4==0: group-granular

        int4   q;
        float4 A, B;
        if (v) {
            q = ids4[m_base + 64 * j + lane];
            A = x4[k_base + 128 * j + 2 * lane];        // points pt0, pt0+1
            B = x4[k_base + 128 * j + 2 * lane + 1];    // points pt0+2, pt0+3
        } else {
            q = make_int4(-1, -1, -1, -1);
            A = make_float4(0.f, 0.f, 0.f, 0.f);
            B = A;
        }

        int cur; float s0, s1, cnt;
        if (q.x == q.w) {
            // Uniform group (sorted => all 4 equal); invalid groups land here.
            cur = q.x;
            s0  = A.x + A.z + B.x + B.z;
            s1  = A.y + A.w + B.y + B.w;
            cnt = (cur >= 0) ? 4.f : 0.f;
        } else {
            // Boundary group (rare): serial run accumulation, flush completed runs.
            cur = q.x; s0 = A.x; s1 = A.y; cnt = 1.f;
            #define PROC(SEG, X0, X1)                              \
                if ((SEG) != cur) {                                \
                    atomicAdd(&acc[4 * cur + 0], s0);              \
                    atomicAdd(&acc[4 * cur + 1], s1);              \
                    atomicAdd(&acc[4 * cur + 2], cnt);             \
                    cur = (SEG); s0 = (X0); s1 = (X1); cnt = 1.f;  \
                } else { s0 += (X0); s1 += (X1); cnt += 1.f; }
            PROC(q.y, A.z, A.w)
            PROC(q.z, B.x, B.y)
            PROC(q.w, B.z, B.w)
            #undef PROC
        }

        // Segmented scan over lane aggregates keyed by cur.
        int prev = __shfl_up(cur, 1);
        bool head = (lane == 0) || (prev != cur);
        uint64_t heads = __ballot(head);
        uint64_t below = heads & (~0ull >> (63 - lane));
        int run_start = 63 - __builtin_clzll(below);

        #pragma unroll
        for (int d = 1; d < 64; d <<= 1) {
            float t0 = __shfl_up(s0, d);
            float t1 = __shfl_up(s1, d);
            float tc = __shfl_up(cnt, d);
            if (lane - d >= run_start) { s0 += t0; s1 += t1; cnt += tc; }
        }

        bool tail = (lane == 63) || ((heads >> (lane + 1)) & 1ull);
        if (tail && cur >= 0) {
            atomicAdd(&acc[4 * cur + 0], s0);
            atomicAdd(&acc[4 * cur + 1], s1);
            atomicAdd(&acc[4 * cur + 2], cnt);
        }
    }
}

// out[s, f] = a0[s]*W[0][f] + a1[s]*W[1][f] + cnt[s]*b[f], float4-vectorized.
__global__ __launch_bounds__(256) void epilogue(
    const float*  __restrict__ acc,  // [4*NSEG]
    const float4* __restrict__ W4,   // [2][64] -> [2][16] float4
    const float4* __restrict__ b4,   // [64] -> [16] float4
    float4* __restrict__ out4)       // [NSEG][16] float4
{
    int idx = blockIdx.x * blockDim.x + threadIdx.x;  // 65536 threads
    int s = idx >> 4;
    int f = idx & 15;
    float a0 = acc[4 * s], a1 = acc[4 * s + 1], c = acc[4 * s + 2];
    float4 w0 = W4[f], w1 = W4[16 + f], bb = b4[f];
    float4 o;
    o.x = a0 * w0.x + a1 * w1.x + c * bb.x;
    o.y = a0 * w0.y + a1 * w1.y + c * bb.y;
    o.z = a0 * w0.z + a1 * w1.z + c * bb.z;
    o.w = a0 * w0.w + a1 * w1.w + c * bb.w;
    out4[idx] = o;
}

extern "C" void kernel_launch(void* const* d_in, const int* in_sizes, int n_in,
                              void* d_out, int out_size, void* d_ws, size_t ws_size,
                              hipStream_t stream) {
    const float4* x4   = (const float4*)d_in[0];  // [N,2] fp32
    const int4*   ids4 = (const int4*)d_in[1];    // [N] int32, sorted
    const float4* W4   = (const float4*)d_in[2];  // [2,64] fp32
    const float4* b4   = (const float4*)d_in[3];  // [64] fp32
    float4* out4 = (float4*)d_out;                // [4096,64] fp32

    const int n = in_sizes[1];                    // 4,000,000
    const int nwave_chunks = (n + 1023) / 1024;   // 3907
    const int nblocks = (nwave_chunks + 3) / 4;   // 977

    float* acc = (float*)d_ws;                    // [4*NSEG]

    hipMemsetAsync(d_ws, 0, 4 * NSEG * sizeof(float), stream);
    seg_reduce<<<nblocks, 256, 0, stream>>>(x4, ids4, acc, n);
    epilogue<<<(NSEG * 64 / 4) / 256, 256, 0, stream>>>(acc, W4, b4, out4);
}